// Round 9
// baseline (211.061 us; speedup 1.0000x reference)
//
#include <hip/hip_runtime.h>

#define N_NODES 50000
#define N_EDGES 800000
#define D 96
#define D4 (D / 4)        // 24 float4 per row
#define SCAN_BLK 196      // 196*256 = 50176 >= 50000

#define HB 128                 // histogram blocks
#define CHUNK (N_EDGES / HB)   // 6250 edges per block
#define NW (N_NODES / 4)       // 12500 packed u32 words (4 x u8 counts)

#define FB_NODES 16            // nodes per fused gather+matmul block
#define RL 12                  // bf16 row = 96*2B = 12 uint4 per node row

// Stage 1: degree counting, u8-packed full-range LDS hist, 2 phases (src,dst).
__global__ void __launch_bounds__(256) hist_kernel(
        const int* __restrict__ src, const int* __restrict__ dst,
        unsigned* __restrict__ hist) {
    __shared__ unsigned hbin[NW];   // 48.8 KB
    int b = blockIdx.x, t = threadIdx.x;
    int e0 = b * CHUNK;
#pragma unroll 1
    for (int p = 0; p < 2; ++p) {
        const int* __restrict__ arr = (p == 0) ? src : dst;
        for (int i = t; i < NW; i += 256) hbin[i] = 0;
        __syncthreads();
        for (int i = t; i < CHUNK; i += 256) {
            int l = arr[e0 + i];
            atomicAdd(&hbin[l >> 2], 1u << ((l & 3) * 8));
        }
        __syncthreads();
        unsigned* __restrict__ g = hist + ((size_t)p * HB + b) * NW;
        for (int i = t; i < NW; i += 256) g[i] = hbin[i];
        __syncthreads();
    }
}

// Stage 2: src hists -> ci; dst hists -> deg_in + in-place exclusive prefix
// along the block dimension (packed u8, carry-free; totals <= ~45).
__global__ void __launch_bounds__(256) reduce_kernel(
        unsigned* __restrict__ hist, float* __restrict__ ci,
        int* __restrict__ deg_in) {
    int w = blockIdx.x * 256 + threadIdx.x;
    if (w >= NW) return;
    const unsigned* __restrict__ ps = hist + w;
    unsigned* __restrict__ pd = hist + (size_t)HB * NW + w;
    unsigned acc_s = 0;
#pragma unroll 8
    for (int b = 0; b < HB; ++b) acc_s += ps[(size_t)b * NW];
    unsigned run = 0;
#pragma unroll 4
    for (int b = 0; b < HB; ++b) {
        unsigned v = pd[(size_t)b * NW];
        pd[(size_t)b * NW] = run;        // exclusive prefix, packed u8
        run += v;
    }
    unsigned acc_d = run;
    int n0 = 4 * w;
    float4 cv;
    cv.x = rsqrtf(fmaxf((float)( acc_s        & 0xFFu), 1.0f));
    cv.y = rsqrtf(fmaxf((float)((acc_s >>  8) & 0xFFu), 1.0f));
    cv.z = rsqrtf(fmaxf((float)((acc_s >> 16) & 0xFFu), 1.0f));
    cv.w = rsqrtf(fmaxf((float)( acc_s >> 24        ), 1.0f));
    *(float4*)&ci[n0] = cv;
    int4 dv;
    dv.x = (int)( acc_d        & 0xFFu);
    dv.y = (int)((acc_d >>  8) & 0xFFu);
    dv.z = (int)((acc_d >> 16) & 0xFFu);
    dv.w = (int)( acc_d >> 24        );
    *(int4*)&deg_in[n0] = dv;
}

// Stage 2.5: sfeat[s] = bf16_rtne(ci[s] * feat[s]) — pre-scaled bf16 rows
// (192 B/row) halve the random-gather traffic and delete per-edge ci loads.
__device__ __forceinline__ unsigned bf16pack(float a, float b) {
    unsigned ua = __float_as_uint(a);
    unsigned ub = __float_as_uint(b);
    ua = (ua + 0x7FFFu + ((ua >> 16) & 1u)) >> 16;       // RTNE
    ub = (ub + 0x7FFFu + ((ub >> 16) & 1u)) & 0xFFFF0000u;
    return ua | ub;
}
__global__ void __launch_bounds__(256) conv_kernel(
        const float4* __restrict__ feat4, const float* __restrict__ ci,
        uint4* __restrict__ sfeat) {
    int t = blockIdx.x * 256 + threadIdx.x;
    if (t >= N_NODES * RL) return;
    int n = t / RL;
    int lane = t - n * RL;
    float c = ci[n];
    float4 a = feat4[n * D4 + lane * 2];
    float4 b = feat4[n * D4 + lane * 2 + 1];
    uint4 o;
    o.x = bf16pack(a.x * c, a.y * c);
    o.y = bf16pack(a.z * c, a.w * c);
    o.z = bf16pack(b.x * c, b.y * c);
    o.w = bf16pack(b.z * c, b.w * c);
    sfeat[t] = o;
}

// Stage 3a: block-local exclusive scan of deg_in -> off, blockSums.
__global__ void __launch_bounds__(256) scanA_kernel(
        const int* __restrict__ deg_in, int* __restrict__ off,
        int* __restrict__ blockSums) {
    __shared__ int s[256];
    int t = threadIdx.x;
    int n = blockIdx.x * 256 + t;
    bool valid = n < N_NODES;
    int deg = valid ? deg_in[n] : 0;
    s[t] = deg;
    __syncthreads();
#pragma unroll
    for (int st = 1; st < 256; st <<= 1) {
        int add = (t >= st) ? s[t - st] : 0;
        __syncthreads();
        s[t] += add;
        __syncthreads();
    }
    int incl = s[t];
    if (valid) off[n] = incl - deg;
    if (t == 255) blockSums[blockIdx.x] = incl;
}

// Stage 3b: add sum(blockSums[0..b-1]) to each block's off entries.
__global__ void __launch_bounds__(256) scan_fin_kernel(
        const int* __restrict__ blockSums, int* __restrict__ off) {
    __shared__ int s[256];
    int t = threadIdx.x, b = blockIdx.x;
    s[t] = (t < b) ? blockSums[t] : 0;
    __syncthreads();
#pragma unroll
    for (int st = 128; st > 0; st >>= 1) {
        if (t < st) s[t] += s[t + st];
        __syncthreads();
    }
    int prefix = s[0];
    int idx = b * 256 + t;
    if (idx < N_NODES) off[idx] += prefix;
}

// Stage 4: atomic-free CSR fill via LDS cursors seeded from the prefix row.
__global__ void __launch_bounds__(512) fill_kernel(
        const int* __restrict__ src, const int* __restrict__ dst,
        const int* __restrict__ off, const unsigned* __restrict__ hist,
        int* __restrict__ csr) {
    __shared__ unsigned cur[NW];   // 48.8 KB
    int b = blockIdx.x, t = threadIdx.x;
    const unsigned* __restrict__ pr = hist + ((size_t)HB + b) * NW;
    for (int i = t; i < NW; i += 512) cur[i] = pr[i];
    __syncthreads();
    int e0 = b * CHUNK;
    for (int i = t; i < CHUNK; i += 512) {
        int d = dst[e0 + i];
        int sh = (d & 3) * 8;
        unsigned old = atomicAdd(&cur[d >> 2], 1u << sh);
        int pos = (int)((old >> sh) & 0xFFu);
        csr[off[d] + pos] = src[e0 + i];
    }
}

// Stage 5 (fused): gather h into LDS, then matmul out = h @ W + bias.
// Gather phase: 12 lanes/node x 8 bf16 elems, 16 nodes per 192-thread block.
// Matmul phase: 48 col-pairs x 4 row-groups, 4 rows x 2 cols per thread.
__global__ void __launch_bounds__(192) fused_kernel(
        const float4* __restrict__ feat4, const uint4* __restrict__ sfeat,
        const int* __restrict__ deg_in, const int* __restrict__ off,
        const int* __restrict__ csr, const float* __restrict__ W,
        const float* __restrict__ bias, float* __restrict__ out) {
    __shared__ float sW[D * D];          // 36 KB
    __shared__ float sh[FB_NODES * D];   // 6 KB
    int tid = threadIdx.x;
    {   // stage W (2304 float4, 12 per thread)
        const float4* __restrict__ w4 = (const float4*)W;
        float4* __restrict__ s4 = (float4*)sW;
        for (int i = tid; i < D * D / 4; i += 192) s4[i] = w4[i];
    }
    // ---- gather phase ----
    int g = tid / RL;            // node 0..15
    int lane = tid - g * RL;     // uint4 index 0..11 (8 floats)
    int n = blockIdx.x * FB_NODES + g;   // 3125*16 = 50000 exact
    int deg = deg_in[n];
    float* __restrict__ hrow = &sh[g * D + lane * 8];
    if (deg == 0) {
        float4 a = feat4[n * D4 + lane * 2];
        float4 b = feat4[n * D4 + lane * 2 + 1];
        *(float4*)hrow = a;
        *(float4*)(hrow + 4) = b;
    } else {
        const int* bk = csr + off[n];
        const uint4* __restrict__ sf = sfeat + lane;
        float acc[8] = {};
        int i = 0;
#define ACC8(v)  { \
        acc[0] += __uint_as_float((v).x << 16); \
        acc[1] += __uint_as_float((v).x & 0xFFFF0000u); \
        acc[2] += __uint_as_float((v).y << 16); \
        acc[3] += __uint_as_float((v).y & 0xFFFF0000u); \
        acc[4] += __uint_as_float((v).z << 16); \
        acc[5] += __uint_as_float((v).z & 0xFFFF0000u); \
        acc[6] += __uint_as_float((v).w << 16); \
        acc[7] += __uint_as_float((v).w & 0xFFFF0000u); }
        for (; i + 1 < deg; i += 2) {
            int s0 = bk[i], s1 = bk[i + 1];
            uint4 v0 = sf[(size_t)s0 * RL];
            uint4 v1 = sf[(size_t)s1 * RL];
            ACC8(v0); ACC8(v1);
        }
        if (i < deg) {
            uint4 v = sf[(size_t)bk[i] * RL];
            ACC8(v);
        }
#undef ACC8
        float cj = rsqrtf((float)deg);
#pragma unroll
        for (int k = 0; k < 8; ++k) hrow[k] = acc[k] * cj;
    }
    __syncthreads();
    // ---- matmul phase ----
    int c = tid % 48;        // cols 2c, 2c+1
    int rg = tid / 48;       // rows 4*rg..4*rg+3
    int r0 = rg * 4;
    int row0 = blockIdx.x * FB_NODES;
    float acc[4][2] = {};
#pragma unroll
    for (int k = 0; k < D; k += 4) {
        float4 hv[4];
#pragma unroll
        for (int r = 0; r < 4; ++r)
            hv[r] = *(const float4*)&sh[(r0 + r) * D + k];
#pragma unroll
        for (int kk = 0; kk < 4; ++kk) {
            float2 w = *(const float2*)&sW[(k + kk) * D + 2 * c];
#pragma unroll
            for (int r = 0; r < 4; ++r) {
                float hval = (&hv[r].x)[kk];
                acc[r][0] = fmaf(hval, w.x, acc[r][0]);
                acc[r][1] = fmaf(hval, w.y, acc[r][1]);
            }
        }
    }
    float2 b = *(const float2*)&bias[2 * c];
#pragma unroll
    for (int r = 0; r < 4; ++r) {
        float2 o;
        o.x = acc[r][0] + b.x;
        o.y = acc[r][1] + b.y;
        *(float2*)&out[(size_t)(row0 + r0 + r) * D + 2 * c] = o;
    }
}

extern "C" void kernel_launch(void* const* d_in, const int* in_sizes, int n_in,
                              void* d_out, int out_size, void* d_ws, size_t ws_size,
                              hipStream_t stream) {
    const float* feat = (const float*)d_in[0];
    const float* W    = (const float*)d_in[1];
    const float* bias = (const float*)d_in[2];
    const int*   src  = (const int*)d_in[3];
    const int*   dst  = (const int*)d_in[4];

    // ws: hist[2*HB*NW] 12.8MB | ci[N] | off[N] | deg_in[N] | blockSums[256] |
    //     csr[E] 3.2MB | sfeat[N*RL uint4] 9.6MB   (~26 MB of 268 MB)
    unsigned* hist      = (unsigned*)d_ws;
    float*    ci        = (float*)(hist + (size_t)2 * HB * NW);
    int*      off       = (int*)(ci + N_NODES);
    int*      deg_in    = off + N_NODES;
    int*      blockSums = deg_in + N_NODES;
    int*      csr       = blockSums + 256;
    uint4*    sfeat     = (uint4*)(csr + N_EDGES);

    hist_kernel<<<HB, 256, 0, stream>>>(src, dst, hist);
    reduce_kernel<<<(NW + 255) / 256, 256, 0, stream>>>(hist, ci, deg_in);
    conv_kernel<<<(N_NODES * RL + 255) / 256, 256, 0, stream>>>(
        (const float4*)feat, ci, sfeat);
    scanA_kernel<<<SCAN_BLK, 256, 0, stream>>>(deg_in, off, blockSums);
    scan_fin_kernel<<<SCAN_BLK, 256, 0, stream>>>(blockSums, off);
    fill_kernel<<<HB, 512, 0, stream>>>(src, dst, off, hist, csr);
    fused_kernel<<<N_NODES / FB_NODES, 192, 0, stream>>>(
        (const float4*)feat, sfeat, deg_in, off, csr, W, bias, (float*)d_out);
}

// Round 10
// 196.578 us; speedup vs baseline: 1.0737x; 1.0737x over previous
//
#include <hip/hip_runtime.h>

#define N_NODES 50000
#define N_EDGES 800000
#define D 96
#define D4 (D / 4)        // 24 float4 per row
#define MM_ROWS 16        // nodes per matmul block
#define SCAN_BLK 196      // 196*256 = 50176 >= 50000

#define HB 128                 // histogram blocks
#define CHUNK (N_EDGES / HB)   // 6250 edges per block
#define NW (N_NODES / 4)       // 12500 packed u32 words (4 x u8 counts)

#define RL 12                  // bf16 row = 96*2B = 12 uint4 per node row

// Stage 1: degree counting, u8-packed full-range LDS hist, 2 phases (src,dst).
__global__ void __launch_bounds__(256) hist_kernel(
        const int* __restrict__ src, const int* __restrict__ dst,
        unsigned* __restrict__ hist) {
    __shared__ unsigned hbin[NW];   // 48.8 KB
    int b = blockIdx.x, t = threadIdx.x;
    int e0 = b * CHUNK;
#pragma unroll 1
    for (int p = 0; p < 2; ++p) {
        const int* __restrict__ arr = (p == 0) ? src : dst;
        for (int i = t; i < NW; i += 256) hbin[i] = 0;
        __syncthreads();
        for (int i = t; i < CHUNK; i += 256) {
            int l = arr[e0 + i];
            atomicAdd(&hbin[l >> 2], 1u << ((l & 3) * 8));
        }
        __syncthreads();
        unsigned* __restrict__ g = hist + ((size_t)p * HB + b) * NW;
        for (int i = t; i < NW; i += 256) g[i] = hbin[i];
        __syncthreads();
    }
}

// Stage 2: src hists -> ci; dst hists -> deg_in + in-place exclusive prefix
// along the block dimension (packed u8, carry-free; totals <= ~45).
__global__ void __launch_bounds__(256) reduce_kernel(
        unsigned* __restrict__ hist, float* __restrict__ ci,
        int* __restrict__ deg_in) {
    int w = blockIdx.x * 256 + threadIdx.x;
    if (w >= NW) return;
    const unsigned* __restrict__ ps = hist + w;
    unsigned* __restrict__ pd = hist + (size_t)HB * NW + w;
    unsigned acc_s = 0;
#pragma unroll 8
    for (int b = 0; b < HB; ++b) acc_s += ps[(size_t)b * NW];
    unsigned run = 0;
#pragma unroll 4
    for (int b = 0; b < HB; ++b) {
        unsigned v = pd[(size_t)b * NW];
        pd[(size_t)b * NW] = run;        // exclusive prefix, packed u8
        run += v;
    }
    unsigned acc_d = run;
    int n0 = 4 * w;
    float4 cv;
    cv.x = rsqrtf(fmaxf((float)( acc_s        & 0xFFu), 1.0f));
    cv.y = rsqrtf(fmaxf((float)((acc_s >>  8) & 0xFFu), 1.0f));
    cv.z = rsqrtf(fmaxf((float)((acc_s >> 16) & 0xFFu), 1.0f));
    cv.w = rsqrtf(fmaxf((float)( acc_s >> 24        ), 1.0f));
    *(float4*)&ci[n0] = cv;
    int4 dv;
    dv.x = (int)( acc_d        & 0xFFu);
    dv.y = (int)((acc_d >>  8) & 0xFFu);
    dv.z = (int)((acc_d >> 16) & 0xFFu);
    dv.w = (int)( acc_d >> 24        );
    *(int4*)&deg_in[n0] = dv;
}

// Stage 2.5: sfeat[s] = bf16_rtne(ci[s] * feat[s]) — pre-scaled bf16 rows
// (192 B/row) halve the random-gather traffic and delete per-edge ci loads.
__device__ __forceinline__ unsigned bf16pack(float a, float b) {
    unsigned ua = __float_as_uint(a);
    unsigned ub = __float_as_uint(b);
    ua = (ua + 0x7FFFu + ((ua >> 16) & 1u)) >> 16;       // RTNE
    ub = (ub + 0x7FFFu + ((ub >> 16) & 1u)) & 0xFFFF0000u;
    return ua | ub;
}
__global__ void __launch_bounds__(256) conv_kernel(
        const float4* __restrict__ feat4, const float* __restrict__ ci,
        uint4* __restrict__ sfeat) {
    int t = blockIdx.x * 256 + threadIdx.x;
    if (t >= N_NODES * RL) return;
    int n = t / RL;
    int lane = t - n * RL;
    float c = ci[n];
    float4 a = feat4[n * D4 + lane * 2];
    float4 b = feat4[n * D4 + lane * 2 + 1];
    uint4 o;
    o.x = bf16pack(a.x * c, a.y * c);
    o.y = bf16pack(a.z * c, a.w * c);
    o.z = bf16pack(b.x * c, b.y * c);
    o.w = bf16pack(b.z * c, b.w * c);
    sfeat[t] = o;
}

// Stage 3a: block-local exclusive scan of deg_in -> off, blockSums.
__global__ void __launch_bounds__(256) scanA_kernel(
        const int* __restrict__ deg_in, int* __restrict__ off,
        int* __restrict__ blockSums) {
    __shared__ int s[256];
    int t = threadIdx.x;
    int n = blockIdx.x * 256 + t;
    bool valid = n < N_NODES;
    int deg = valid ? deg_in[n] : 0;
    s[t] = deg;
    __syncthreads();
#pragma unroll
    for (int st = 1; st < 256; st <<= 1) {
        int add = (t >= st) ? s[t - st] : 0;
        __syncthreads();
        s[t] += add;
        __syncthreads();
    }
    int incl = s[t];
    if (valid) off[n] = incl - deg;
    if (t == 255) blockSums[blockIdx.x] = incl;
}

// Stage 3b: add sum(blockSums[0..b-1]) to each block's off entries.
__global__ void __launch_bounds__(256) scan_fin_kernel(
        const int* __restrict__ blockSums, int* __restrict__ off) {
    __shared__ int s[256];
    int t = threadIdx.x, b = blockIdx.x;
    s[t] = (t < b) ? blockSums[t] : 0;
    __syncthreads();
#pragma unroll
    for (int st = 128; st > 0; st >>= 1) {
        if (t < st) s[t] += s[t + st];
        __syncthreads();
    }
    int prefix = s[0];
    int idx = b * 256 + t;
    if (idx < N_NODES) off[idx] += prefix;
}

// Stage 4: atomic-free CSR fill via LDS cursors seeded from the prefix row.
__global__ void __launch_bounds__(512) fill_kernel(
        const int* __restrict__ src, const int* __restrict__ dst,
        const int* __restrict__ off, const unsigned* __restrict__ hist,
        int* __restrict__ csr) {
    __shared__ unsigned cur[NW];   // 48.8 KB
    int b = blockIdx.x, t = threadIdx.x;
    const unsigned* __restrict__ pr = hist + ((size_t)HB + b) * NW;
    for (int i = t; i < NW; i += 512) cur[i] = pr[i];
    __syncthreads();
    int e0 = b * CHUNK;
    for (int i = t; i < CHUNK; i += 512) {
        int d = dst[e0 + i];
        int sh = (d & 3) * 8;
        unsigned old = atomicAdd(&cur[d >> 2], 1u << sh);
        int pos = (int)((old >> sh) & 0xFFu);
        csr[off[d] + pos] = src[e0 + i];
    }
}

// Stage 5: gather h = deg>0 ? cj * sum sfeat[s] : feat[n], write fp32 to d_out.
// 12 lanes/node (one uint4 = 8 bf16 each), 16 nodes per 192-thread block.
// No LDS -> high occupancy; 4-way unroll for outstanding-miss parallelism.
__global__ void __launch_bounds__(192) gather_kernel(
        const float4* __restrict__ feat4, const uint4* __restrict__ sfeat,
        const int* __restrict__ deg_in, const int* __restrict__ off,
        const int* __restrict__ csr, float* __restrict__ out) {
    int tid = threadIdx.x;
    int g = tid / RL;            // node 0..15
    int lane = tid - g * RL;     // uint4 index 0..11 (8 floats)
    int n = blockIdx.x * 16 + g; // 3125*16 = 50000 exact
    int deg = deg_in[n];
    float* __restrict__ hrow = out + (size_t)n * D + lane * 8;
    if (deg == 0) {
        float4 a = feat4[n * D4 + lane * 2];
        float4 b = feat4[n * D4 + lane * 2 + 1];
        *(float4*)hrow = a;
        *(float4*)(hrow + 4) = b;
        return;
    }
    const int* bk = csr + off[n];
    const uint4* __restrict__ sf = sfeat + lane;
    float acc[8] = {};
#define ACC8(v)  { \
    acc[0] += __uint_as_float((v).x << 16); \
    acc[1] += __uint_as_float((v).x & 0xFFFF0000u); \
    acc[2] += __uint_as_float((v).y << 16); \
    acc[3] += __uint_as_float((v).y & 0xFFFF0000u); \
    acc[4] += __uint_as_float((v).z << 16); \
    acc[5] += __uint_as_float((v).z & 0xFFFF0000u); \
    acc[6] += __uint_as_float((v).w << 16); \
    acc[7] += __uint_as_float((v).w & 0xFFFF0000u); }
    int i = 0;
    for (; i + 3 < deg; i += 4) {
        int s0 = bk[i], s1 = bk[i + 1], s2 = bk[i + 2], s3 = bk[i + 3];
        uint4 v0 = sf[(size_t)s0 * RL];
        uint4 v1 = sf[(size_t)s1 * RL];
        uint4 v2 = sf[(size_t)s2 * RL];
        uint4 v3 = sf[(size_t)s3 * RL];
        ACC8(v0); ACC8(v1); ACC8(v2); ACC8(v3);
    }
    for (; i < deg; ++i) {
        uint4 v = sf[(size_t)bk[i] * RL];
        ACC8(v);
    }
#undef ACC8
    float cj = rsqrtf((float)deg);
    float4 o0 = {acc[0] * cj, acc[1] * cj, acc[2] * cj, acc[3] * cj};
    float4 o1 = {acc[4] * cj, acc[5] * cj, acc[6] * cj, acc[7] * cj};
    *(float4*)hrow = o0;
    *(float4*)(hrow + 4) = o1;
}

// Stage 6: in-place out = h @ W + bias. W + 16 h-rows staged in LDS.
__global__ void __launch_bounds__(192) matmul_kernel(
        const float* __restrict__ W, const float* __restrict__ bias,
        float* __restrict__ out) {
    __shared__ float sW[D * D];        // 36 KB
    __shared__ float sh[MM_ROWS * D];  // 6 KB
    int tid = threadIdx.x;
    {
        const float4* __restrict__ w4 = (const float4*)W;
        float4* __restrict__ s4 = (float4*)sW;
        for (int i = tid; i < D * D / 4; i += 192) s4[i] = w4[i];
    }
    int row0 = blockIdx.x * MM_ROWS;
    const float4* hg = (const float4*)(out + (size_t)row0 * D);
    float4* sh4 = (float4*)sh;
    for (int i = tid; i < MM_ROWS * D4; i += 192) sh4[i] = hg[i];
    __syncthreads();

    int c = tid % 48;        // cols 2c, 2c+1
    int rg = tid / 48;       // rows 4*rg..4*rg+3
    int r0 = rg * 4;
    float acc[4][2] = {};
#pragma unroll
    for (int k = 0; k < D; k += 4) {
        float4 hv[4];
#pragma unroll
        for (int r = 0; r < 4; ++r)
            hv[r] = *(const float4*)&sh[(r0 + r) * D + k];
#pragma unroll
        for (int kk = 0; kk < 4; ++kk) {
            float2 w = *(const float2*)&sW[(k + kk) * D + 2 * c];
#pragma unroll
            for (int r = 0; r < 4; ++r) {
                float hval = (&hv[r].x)[kk];
                acc[r][0] = fmaf(hval, w.x, acc[r][0]);
                acc[r][1] = fmaf(hval, w.y, acc[r][1]);
            }
        }
    }
    float2 b = *(const float2*)&bias[2 * c];
#pragma unroll
    for (int r = 0; r < 4; ++r) {
        float2 o;
        o.x = acc[r][0] + b.x;
        o.y = acc[r][1] + b.y;
        *(float2*)&out[(size_t)(row0 + r0 + r) * D + 2 * c] = o;
    }
}

extern "C" void kernel_launch(void* const* d_in, const int* in_sizes, int n_in,
                              void* d_out, int out_size, void* d_ws, size_t ws_size,
                              hipStream_t stream) {
    const float* feat = (const float*)d_in[0];
    const float* W    = (const float*)d_in[1];
    const float* bias = (const float*)d_in[2];
    const int*   src  = (const int*)d_in[3];
    const int*   dst  = (const int*)d_in[4];

    // ws: hist[2*HB*NW] 12.8MB | ci[N] | off[N] | deg_in[N] | blockSums[256] |
    //     csr[E] 3.2MB | sfeat[N*RL uint4] 9.6MB
    unsigned* hist      = (unsigned*)d_ws;
    float*    ci        = (float*)(hist + (size_t)2 * HB * NW);
    int*      off       = (int*)(ci + N_NODES);
    int*      deg_in    = off + N_NODES;
    int*      blockSums = deg_in + N_NODES;
    int*      csr       = blockSums + 256;
    uint4*    sfeat     = (uint4*)(csr + N_EDGES);

    hist_kernel<<<HB, 256, 0, stream>>>(src, dst, hist);
    reduce_kernel<<<(NW + 255) / 256, 256, 0, stream>>>(hist, ci, deg_in);
    conv_kernel<<<(N_NODES * RL + 255) / 256, 256, 0, stream>>>(
        (const float4*)feat, ci, sfeat);
    scanA_kernel<<<SCAN_BLK, 256, 0, stream>>>(deg_in, off, blockSums);
    scan_fin_kernel<<<SCAN_BLK, 256, 0, stream>>>(blockSums, off);
    fill_kernel<<<HB, 512, 0, stream>>>(src, dst, off, hist, csr);
    gather_kernel<<<N_NODES / 16, 192, 0, stream>>>(
        (const float4*)feat, sfeat, deg_in, off, csr, (float*)d_out);
    matmul_kernel<<<N_NODES / MM_ROWS, 192, 0, stream>>>(W, bias, (float*)d_out);
}

// Round 11
// 173.830 us; speedup vs baseline: 1.2142x; 1.1309x over previous
//
#include <hip/hip_runtime.h>

#define N_NODES 50000
#define N_EDGES 800000
#define D 96
#define D4 (D / 4)        // 24 float4 per row
#define SCAN_BLK 196      // 196*256 = 50176 >= 50000

#define HB 128                 // histogram blocks
#define CHUNK (N_EDGES / HB)   // 6250 edges per block
#define NW (N_NODES / 4)       // 12500 packed u32 words (4 x u8 counts)

#define RL 12                  // bf16 row = 96*2B = 12 uint4 per node row
#define NTILES (N_NODES / 16)  // 3125 16-row MFMA tiles

typedef __attribute__((ext_vector_type(8))) short short8;
typedef __attribute__((ext_vector_type(4))) float floatx4;

__device__ __forceinline__ short8 as_short8(uint4 u) { return *(short8*)&u; }

// Stage 1: degree counting, u8-packed full-range LDS hist, 2 phases (src,dst).
__global__ void __launch_bounds__(256) hist_kernel(
        const int* __restrict__ src, const int* __restrict__ dst,
        unsigned* __restrict__ hist) {
    __shared__ unsigned hbin[NW];   // 48.8 KB
    int b = blockIdx.x, t = threadIdx.x;
    int e0 = b * CHUNK;
#pragma unroll 1
    for (int p = 0; p < 2; ++p) {
        const int* __restrict__ arr = (p == 0) ? src : dst;
        for (int i = t; i < NW; i += 256) hbin[i] = 0;
        __syncthreads();
        for (int i = t; i < CHUNK; i += 256) {
            int l = arr[e0 + i];
            atomicAdd(&hbin[l >> 2], 1u << ((l & 3) * 8));
        }
        __syncthreads();
        unsigned* __restrict__ g = hist + ((size_t)p * HB + b) * NW;
        for (int i = t; i < NW; i += 256) g[i] = hbin[i];
        __syncthreads();
    }
}

// Stage 2: src hists -> ci; dst hists -> deg_in + in-place exclusive prefix
// along the block dimension (packed u8, carry-free; totals <= ~45).
__global__ void __launch_bounds__(256) reduce_kernel(
        unsigned* __restrict__ hist, float* __restrict__ ci,
        int* __restrict__ deg_in) {
    int w = blockIdx.x * 256 + threadIdx.x;
    if (w >= NW) return;
    const unsigned* __restrict__ ps = hist + w;
    unsigned* __restrict__ pd = hist + (size_t)HB * NW + w;
    unsigned acc_s = 0;
#pragma unroll 8
    for (int b = 0; b < HB; ++b) acc_s += ps[(size_t)b * NW];
    unsigned run = 0;
#pragma unroll 4
    for (int b = 0; b < HB; ++b) {
        unsigned v = pd[(size_t)b * NW];
        pd[(size_t)b * NW] = run;        // exclusive prefix, packed u8
        run += v;
    }
    unsigned acc_d = run;
    int n0 = 4 * w;
    float4 cv;
    cv.x = rsqrtf(fmaxf((float)( acc_s        & 0xFFu), 1.0f));
    cv.y = rsqrtf(fmaxf((float)((acc_s >>  8) & 0xFFu), 1.0f));
    cv.z = rsqrtf(fmaxf((float)((acc_s >> 16) & 0xFFu), 1.0f));
    cv.w = rsqrtf(fmaxf((float)( acc_s >> 24        ), 1.0f));
    *(float4*)&ci[n0] = cv;
    int4 dv;
    dv.x = (int)( acc_d        & 0xFFu);
    dv.y = (int)((acc_d >>  8) & 0xFFu);
    dv.z = (int)((acc_d >> 16) & 0xFFu);
    dv.w = (int)( acc_d >> 24        );
    *(int4*)&deg_in[n0] = dv;
}

// bf16 RTNE pack: a -> low 16, b -> high 16.
__device__ __forceinline__ unsigned bf16pack(float a, float b) {
    unsigned ua = __float_as_uint(a);
    unsigned ub = __float_as_uint(b);
    ua = (ua + 0x7FFFu + ((ua >> 16) & 1u)) >> 16;       // RTNE
    ub = (ub + 0x7FFFu + ((ub >> 16) & 1u)) & 0xFFFF0000u;
    return ua | ub;
}

// Stage 2.5: sfeat[s] = bf16_rtne(ci[s] * feat[s]) — pre-scaled bf16 rows.
__global__ void __launch_bounds__(256) conv_kernel(
        const float4* __restrict__ feat4, const float* __restrict__ ci,
        uint4* __restrict__ sfeat) {
    int t = blockIdx.x * 256 + threadIdx.x;
    if (t >= N_NODES * RL) return;
    int n = t / RL;
    int lane = t - n * RL;
    float c = ci[n];
    float4 a = feat4[n * D4 + lane * 2];
    float4 b = feat4[n * D4 + lane * 2 + 1];
    uint4 o;
    o.x = bf16pack(a.x * c, a.y * c);
    o.y = bf16pack(a.z * c, a.w * c);
    o.z = bf16pack(b.x * c, b.y * c);
    o.w = bf16pack(b.z * c, b.w * c);
    sfeat[t] = o;
}

// Stage 2.6: WT[n][k] = bf16(W[k][n]) — B-fragment-friendly transposed bf16 W.
// One thread per (n, k-pair). 18 KB output, fully cached downstream.
__global__ void __launch_bounds__(256) wprep_kernel(
        const float* __restrict__ W, unsigned* __restrict__ WT32) {
    int t = blockIdx.x * 256 + threadIdx.x;
    if (t >= D * (D / 2)) return;     // 96*48
    int n = t / (D / 2);
    int j = t - n * (D / 2);          // k-pair index
    float w0 = W[(2 * j) * D + n];
    float w1 = W[(2 * j + 1) * D + n];
    WT32[n * (D / 2) + j] = bf16pack(w0, w1);
}

// Stage 3a: block-local exclusive scan of deg_in -> off, blockSums.
__global__ void __launch_bounds__(256) scanA_kernel(
        const int* __restrict__ deg_in, int* __restrict__ off,
        int* __restrict__ blockSums) {
    __shared__ int s[256];
    int t = threadIdx.x;
    int n = blockIdx.x * 256 + t;
    bool valid = n < N_NODES;
    int deg = valid ? deg_in[n] : 0;
    s[t] = deg;
    __syncthreads();
#pragma unroll
    for (int st = 1; st < 256; st <<= 1) {
        int add = (t >= st) ? s[t - st] : 0;
        __syncthreads();
        s[t] += add;
        __syncthreads();
    }
    int incl = s[t];
    if (valid) off[n] = incl - deg;
    if (t == 255) blockSums[blockIdx.x] = incl;
}

// Stage 3b: add sum(blockSums[0..b-1]) to each block's off entries.
__global__ void __launch_bounds__(256) scan_fin_kernel(
        const int* __restrict__ blockSums, int* __restrict__ off) {
    __shared__ int s[256];
    int t = threadIdx.x, b = blockIdx.x;
    s[t] = (t < b) ? blockSums[t] : 0;
    __syncthreads();
#pragma unroll
    for (int st = 128; st > 0; st >>= 1) {
        if (t < st) s[t] += s[t + st];
        __syncthreads();
    }
    int prefix = s[0];
    int idx = b * 256 + t;
    if (idx < N_NODES) off[idx] += prefix;
}

// Stage 4: atomic-free CSR fill via LDS cursors seeded from the prefix row.
__global__ void __launch_bounds__(512) fill_kernel(
        const int* __restrict__ src, const int* __restrict__ dst,
        const int* __restrict__ off, const unsigned* __restrict__ hist,
        int* __restrict__ csr) {
    __shared__ unsigned cur[NW];   // 48.8 KB
    int b = blockIdx.x, t = threadIdx.x;
    const unsigned* __restrict__ pr = hist + ((size_t)HB + b) * NW;
    for (int i = t; i < NW; i += 512) cur[i] = pr[i];
    __syncthreads();
    int e0 = b * CHUNK;
    for (int i = t; i < CHUNK; i += 512) {
        int d = dst[e0 + i];
        int sh = (d & 3) * 8;
        unsigned old = atomicAdd(&cur[d >> 2], 1u << sh);
        int pos = (int)((old >> sh) & 0xFFu);
        csr[off[d] + pos] = src[e0 + i];
    }
}

// Stage 5: gather h = deg>0 ? cj * sum sfeat[s] : feat[n], write BF16 to hbuf.
// 12 lanes/node (one uint4 = 8 bf16 each), 16 nodes per 192-thread block.
__global__ void __launch_bounds__(192) gather_kernel(
        const float4* __restrict__ feat4, const uint4* __restrict__ sfeat,
        const int* __restrict__ deg_in, const int* __restrict__ off,
        const int* __restrict__ csr, uint4* __restrict__ hbuf) {
    int tid = threadIdx.x;
    int g = tid / RL;            // node 0..15
    int lane = tid - g * RL;     // uint4 index 0..11 (8 bf16)
    int n = blockIdx.x * 16 + g; // 3125*16 = 50000 exact
    int deg = deg_in[n];
    uint4* __restrict__ hout = hbuf + (size_t)n * RL + lane;
    if (deg == 0) {
        float4 a = feat4[n * D4 + lane * 2];
        float4 b = feat4[n * D4 + lane * 2 + 1];
        uint4 o;
        o.x = bf16pack(a.x, a.y);
        o.y = bf16pack(a.z, a.w);
        o.z = bf16pack(b.x, b.y);
        o.w = bf16pack(b.z, b.w);
        *hout = o;
        return;
    }
    const int* bk = csr + off[n];
    const uint4* __restrict__ sf = sfeat + lane;
    float acc[8] = {};
#define ACC8(v)  { \
    acc[0] += __uint_as_float((v).x << 16); \
    acc[1] += __uint_as_float((v).x & 0xFFFF0000u); \
    acc[2] += __uint_as_float((v).y << 16); \
    acc[3] += __uint_as_float((v).y & 0xFFFF0000u); \
    acc[4] += __uint_as_float((v).z << 16); \
    acc[5] += __uint_as_float((v).z & 0xFFFF0000u); \
    acc[6] += __uint_as_float((v).w << 16); \
    acc[7] += __uint_as_float((v).w & 0xFFFF0000u); }
    int i = 0;
    for (; i + 3 < deg; i += 4) {
        int s0 = bk[i], s1 = bk[i + 1], s2 = bk[i + 2], s3 = bk[i + 3];
        uint4 v0 = sf[(size_t)s0 * RL];
        uint4 v1 = sf[(size_t)s1 * RL];
        uint4 v2 = sf[(size_t)s2 * RL];
        uint4 v3 = sf[(size_t)s3 * RL];
        ACC8(v0); ACC8(v1); ACC8(v2); ACC8(v3);
    }
    for (; i < deg; ++i) {
        uint4 v = sf[(size_t)bk[i] * RL];
        ACC8(v);
    }
#undef ACC8
    float cj = rsqrtf((float)deg);
    uint4 o;
    o.x = bf16pack(acc[0] * cj, acc[1] * cj);
    o.y = bf16pack(acc[2] * cj, acc[3] * cj);
    o.z = bf16pack(acc[4] * cj, acc[5] * cj);
    o.w = bf16pack(acc[6] * cj, acc[7] * cj);
    *hout = o;
}

// Stage 6: out = h @ W + bias via mfma_f32_16x16x32_bf16. Zero LDS.
// One wave per 16-row tile; A-frags (3 chunks of K=96) reused across all
// 6 col-tiles; B-frags from WT (L1-resident 18 KB).
// Layouts (m89/m91-verified): A[m=lane&15][k=quad*8+j]; B[k=quad*8+j][n=lane&15];
// D col=lane&15, row=quad*4+reg.
__global__ void __launch_bounds__(256) mfma_mm_kernel(
        const uint4* __restrict__ hb4, const uint4* __restrict__ wt4,
        const float* __restrict__ bias, float* __restrict__ out) {
    int wave = threadIdx.x >> 6;
    int lane = threadIdx.x & 63;
    int tile = blockIdx.x * 4 + wave;
    if (tile >= NTILES) return;
    int m = lane & 15, quad = lane >> 4;
    int row0 = tile * 16;
    int rb = (row0 + m) * RL + quad;
    short8 a0 = as_short8(hb4[rb]);      // kc=0
    short8 a1 = as_short8(hb4[rb + 4]);  // kc=1
    short8 a2 = as_short8(hb4[rb + 8]);  // kc=2
    int r_out0 = row0 + quad * 4;
#pragma unroll
    for (int ct = 0; ct < 6; ++ct) {
        int n = ct * 16 + m;
        int wb = n * RL + quad;
        short8 b0 = as_short8(wt4[wb]);
        short8 b1 = as_short8(wt4[wb + 4]);
        short8 b2 = as_short8(wt4[wb + 8]);
        floatx4 c = {0.f, 0.f, 0.f, 0.f};
        c = __builtin_amdgcn_mfma_f32_16x16x32_bf16(a0, b0, c, 0, 0, 0);
        c = __builtin_amdgcn_mfma_f32_16x16x32_bf16(a1, b1, c, 0, 0, 0);
        c = __builtin_amdgcn_mfma_f32_16x16x32_bf16(a2, b2, c, 0, 0, 0);
        float bs = bias[n];
#pragma unroll
        for (int r = 0; r < 4; ++r)
            out[(size_t)(r_out0 + r) * D + n] = c[r] + bs;
    }
}

extern "C" void kernel_launch(void* const* d_in, const int* in_sizes, int n_in,
                              void* d_out, int out_size, void* d_ws, size_t ws_size,
                              hipStream_t stream) {
    const float* feat = (const float*)d_in[0];
    const float* W    = (const float*)d_in[1];
    const float* bias = (const float*)d_in[2];
    const int*   src  = (const int*)d_in[3];
    const int*   dst  = (const int*)d_in[4];

    // ws: hist 12.8MB | ci[N] | off[N] | deg_in[N] | blockSums[256] |
    //     csr[E] 3.2MB | sfeat 9.6MB | hbuf 9.6MB | WT 18KB   (~36 MB of 268 MB)
    unsigned* hist      = (unsigned*)d_ws;
    float*    ci        = (float*)(hist + (size_t)2 * HB * NW);
    int*      off       = (int*)(ci + N_NODES);
    int*      deg_in    = off + N_NODES;
    int*      blockSums = deg_in + N_NODES;
    int*      csr       = blockSums + 256;
    uint4*    sfeat     = (uint4*)(csr + N_EDGES);
    uint4*    hbuf      = sfeat + (size_t)N_NODES * RL;
    unsigned* WT32      = (unsigned*)(hbuf + (size_t)N_NODES * RL);

    hist_kernel<<<HB, 256, 0, stream>>>(src, dst, hist);
    reduce_kernel<<<(NW + 255) / 256, 256, 0, stream>>>(hist, ci, deg_in);
    conv_kernel<<<(N_NODES * RL + 255) / 256, 256, 0, stream>>>(
        (const float4*)feat, ci, sfeat);
    wprep_kernel<<<(D * (D / 2) + 255) / 256, 256, 0, stream>>>(W, WT32);
    scanA_kernel<<<SCAN_BLK, 256, 0, stream>>>(deg_in, off, blockSums);
    scan_fin_kernel<<<SCAN_BLK, 256, 0, stream>>>(blockSums, off);
    fill_kernel<<<HB, 512, 0, stream>>>(src, dst, off, hist, csr);
    gather_kernel<<<N_NODES / 16, 192, 0, stream>>>(
        (const float4*)feat, sfeat, deg_in, off, csr, hbuf);
    mfma_mm_kernel<<<(NTILES + 3) / 4, 256, 0, stream>>>(
        hbuf, (const uint4*)WT32, bias, (float*)d_out);
}

// Round 12
// 173.501 us; speedup vs baseline: 1.2165x; 1.0019x over previous
//
#include <hip/hip_runtime.h>

#define N_NODES 50000
#define N_EDGES 800000
#define D 96
#define D4 (D / 4)        // 24 float4 per row
#define SCAN_BLK 196      // 196*256 = 50176 >= 50000

#define HB 128                 // histogram blocks
#define CHUNK (N_EDGES / HB)   // 6250 edges per block
#define NW (N_NODES / 4)       // 12500 packed u32 words (4 x u8 counts)

#define RL 12                  // bf16 row = 96*2B = 12 uint4 per node row
#define CL 4                   // uint4 per row per column-chunk (32 cols)
#define NPASS 3                // column chunks in gather
#define GN 48                  // nodes per gather block (192 thr / 4 lanes)
#define NTILES (N_NODES / 16)  // 3125 16-row MFMA tiles

typedef __attribute__((ext_vector_type(8))) short short8;
typedef __attribute__((ext_vector_type(4))) float floatx4;

__device__ __forceinline__ short8 as_short8(uint4 u) { return *(short8*)&u; }

// Stage 1: degree counting, u8-packed full-range LDS hist, 2 phases (src,dst).
// 1024 threads: zero/flush loops are 13 iters instead of 49.
__global__ void __launch_bounds__(1024) hist_kernel(
        const int* __restrict__ src, const int* __restrict__ dst,
        unsigned* __restrict__ hist) {
    __shared__ unsigned hbin[NW];   // 48.8 KB
    int b = blockIdx.x, t = threadIdx.x;
    int e0 = b * CHUNK;
#pragma unroll 1
    for (int p = 0; p < 2; ++p) {
        const int* __restrict__ arr = (p == 0) ? src : dst;
        for (int i = t; i < NW; i += 1024) hbin[i] = 0;
        __syncthreads();
        for (int i = t; i < CHUNK; i += 1024) {
            int l = arr[e0 + i];
            atomicAdd(&hbin[l >> 2], 1u << ((l & 3) * 8));
        }
        __syncthreads();
        unsigned* __restrict__ g = hist + ((size_t)p * HB + b) * NW;
        for (int i = t; i < NW; i += 1024) g[i] = hbin[i];
        __syncthreads();
    }
}

// Stage 2: src hists -> ci; dst hists -> deg_in + in-place exclusive prefix
// along the block dimension (packed u8, carry-free; totals <= ~45).
__global__ void __launch_bounds__(256) reduce_kernel(
        unsigned* __restrict__ hist, float* __restrict__ ci,
        int* __restrict__ deg_in) {
    int w = blockIdx.x * 256 + threadIdx.x;
    if (w >= NW) return;
    const unsigned* __restrict__ ps = hist + w;
    unsigned* __restrict__ pd = hist + (size_t)HB * NW + w;
    unsigned acc_s = 0;
#pragma unroll 8
    for (int b = 0; b < HB; ++b) acc_s += ps[(size_t)b * NW];
    unsigned run = 0;
#pragma unroll 4
    for (int b = 0; b < HB; ++b) {
        unsigned v = pd[(size_t)b * NW];
        pd[(size_t)b * NW] = run;        // exclusive prefix, packed u8
        run += v;
    }
    unsigned acc_d = run;
    int n0 = 4 * w;
    float4 cv;
    cv.x = rsqrtf(fmaxf((float)( acc_s        & 0xFFu), 1.0f));
    cv.y = rsqrtf(fmaxf((float)((acc_s >>  8) & 0xFFu), 1.0f));
    cv.z = rsqrtf(fmaxf((float)((acc_s >> 16) & 0xFFu), 1.0f));
    cv.w = rsqrtf(fmaxf((float)( acc_s >> 24        ), 1.0f));
    *(float4*)&ci[n0] = cv;
    int4 dv;
    dv.x = (int)( acc_d        & 0xFFu);
    dv.y = (int)((acc_d >>  8) & 0xFFu);
    dv.z = (int)((acc_d >> 16) & 0xFFu);
    dv.w = (int)( acc_d >> 24        );
    *(int4*)&deg_in[n0] = dv;
}

// bf16 RTNE pack: a -> low 16, b -> high 16.
__device__ __forceinline__ unsigned bf16pack(float a, float b) {
    unsigned ua = __float_as_uint(a);
    unsigned ub = __float_as_uint(b);
    ua = (ua + 0x7FFFu + ((ua >> 16) & 1u)) >> 16;       // RTNE
    ub = (ub + 0x7FFFu + ((ub >> 16) & 1u)) & 0xFFFF0000u;
    return ua | ub;
}

// Stage 2.5: sfeat = bf16_rtne(ci * feat), CHUNK-MAJOR layout:
// sfeat[(pass*N + n)*CL + sub] holds cols pass*32 .. pass*32+31 of node n.
// Each gather pass then random-reads a contiguous 3.2 MB region (L2-resident).
__global__ void __launch_bounds__(256) conv_kernel(
        const float4* __restrict__ feat4, const float* __restrict__ ci,
        uint4* __restrict__ sfeat) {
    int t = blockIdx.x * 256 + threadIdx.x;
    if (t >= N_NODES * RL) return;
    int n = t / RL;
    int lane = t - n * RL;
    int pass = lane >> 2;      // 0..2
    int sub = lane & 3;        // 0..3
    float c = ci[n];
    float4 a = feat4[n * D4 + lane * 2];
    float4 b = feat4[n * D4 + lane * 2 + 1];
    uint4 o;
    o.x = bf16pack(a.x * c, a.y * c);
    o.y = bf16pack(a.z * c, a.w * c);
    o.z = bf16pack(b.x * c, b.y * c);
    o.w = bf16pack(b.z * c, b.w * c);
    sfeat[((size_t)pass * N_NODES + n) * CL + sub] = o;
}

// Stage 2.6: WT[n][k] = bf16(W[k][n]) — B-fragment-friendly transposed bf16 W.
__global__ void __launch_bounds__(256) wprep_kernel(
        const float* __restrict__ W, unsigned* __restrict__ WT32) {
    int t = blockIdx.x * 256 + threadIdx.x;
    if (t >= D * (D / 2)) return;     // 96*48
    int n = t / (D / 2);
    int j = t - n * (D / 2);          // k-pair index
    float w0 = W[(2 * j) * D + n];
    float w1 = W[(2 * j + 1) * D + n];
    WT32[n * (D / 2) + j] = bf16pack(w0, w1);
}

// Stage 3a: block-local exclusive scan of deg_in -> off, blockSums.
__global__ void __launch_bounds__(256) scanA_kernel(
        const int* __restrict__ deg_in, int* __restrict__ off,
        int* __restrict__ blockSums) {
    __shared__ int s[256];
    int t = threadIdx.x;
    int n = blockIdx.x * 256 + t;
    bool valid = n < N_NODES;
    int deg = valid ? deg_in[n] : 0;
    s[t] = deg;
    __syncthreads();
#pragma unroll
    for (int st = 1; st < 256; st <<= 1) {
        int add = (t >= st) ? s[t - st] : 0;
        __syncthreads();
        s[t] += add;
        __syncthreads();
    }
    int incl = s[t];
    if (valid) off[n] = incl - deg;
    if (t == 255) blockSums[blockIdx.x] = incl;
}

// Stage 3b: add sum(blockSums[0..b-1]) to each block's off entries.
__global__ void __launch_bounds__(256) scan_fin_kernel(
        const int* __restrict__ blockSums, int* __restrict__ off) {
    __shared__ int s[256];
    int t = threadIdx.x, b = blockIdx.x;
    s[t] = (t < b) ? blockSums[t] : 0;
    __syncthreads();
#pragma unroll
    for (int st = 128; st > 0; st >>= 1) {
        if (t < st) s[t] += s[t + st];
        __syncthreads();
    }
    int prefix = s[0];
    int idx = b * 256 + t;
    if (idx < N_NODES) off[idx] += prefix;
}

// Stage 4: atomic-free CSR fill via LDS cursors seeded from the prefix row.
__global__ void __launch_bounds__(1024) fill_kernel(
        const int* __restrict__ src, const int* __restrict__ dst,
        const int* __restrict__ off, const unsigned* __restrict__ hist,
        int* __restrict__ csr) {
    __shared__ unsigned cur[NW];   // 48.8 KB
    int b = blockIdx.x, t = threadIdx.x;
    const unsigned* __restrict__ pr = hist + ((size_t)HB + b) * NW;
    for (int i = t; i < NW; i += 1024) cur[i] = pr[i];
    __syncthreads();
    int e0 = b * CHUNK;
    for (int i = t; i < CHUNK; i += 1024) {
        int d = dst[e0 + i];
        int sh = (d & 3) * 8;
        unsigned old = atomicAdd(&cur[d >> 2], 1u << sh);
        int pos = (int)((old >> sh) & 0xFFu);
        csr[off[d] + pos] = src[e0 + i];
    }
}

// Stage 5: gather, column-split. blockIdx.y = pass (0..2); each pass
// random-reads only its 3.2 MB sfeat chunk -> per-XCD L2 resident.
// 4 lanes/node (one uint4 = 8 bf16), 48 nodes per 192-thread block.
__global__ void __launch_bounds__(192) gather_kernel(
        const float4* __restrict__ feat4, const uint4* __restrict__ sfeat,
        const int* __restrict__ deg_in, const int* __restrict__ off,
        const int* __restrict__ csr, uint4* __restrict__ hbuf) {
    int tid = threadIdx.x;
    int pass = blockIdx.y;
    int g = tid >> 2;            // node 0..47
    int lane = tid & 3;          // uint4 index within chunk
    int n = blockIdx.x * GN + g;
    if (n >= N_NODES) return;
    int deg = deg_in[n];
    uint4* __restrict__ hout = hbuf + (size_t)n * RL + pass * CL + lane;
    if (deg == 0) {
        int fb = n * D4 + pass * 8 + lane * 2;
        float4 a = feat4[fb];
        float4 b = feat4[fb + 1];
        uint4 o;
        o.x = bf16pack(a.x, a.y);
        o.y = bf16pack(a.z, a.w);
        o.z = bf16pack(b.x, b.y);
        o.w = bf16pack(b.z, b.w);
        *hout = o;
        return;
    }
    const int* bk = csr + off[n];
    const uint4* __restrict__ sf = sfeat + (size_t)pass * N_NODES * CL + lane;
    float acc[8] = {};
#define ACC8(v)  { \
    acc[0] += __uint_as_float((v).x << 16); \
    acc[1] += __uint_as_float((v).x & 0xFFFF0000u); \
    acc[2] += __uint_as_float((v).y << 16); \
    acc[3] += __uint_as_float((v).y & 0xFFFF0000u); \
    acc[4] += __uint_as_float((v).z << 16); \
    acc[5] += __uint_as_float((v).z & 0xFFFF0000u); \
    acc[6] += __uint_as_float((v).w << 16); \
    acc[7] += __uint_as_float((v).w & 0xFFFF0000u); }
    int i = 0;
    for (; i + 3 < deg; i += 4) {
        int s0 = bk[i], s1 = bk[i + 1], s2 = bk[i + 2], s3 = bk[i + 3];
        uint4 v0 = sf[(size_t)s0 * CL];
        uint4 v1 = sf[(size_t)s1 * CL];
        uint4 v2 = sf[(size_t)s2 * CL];
        uint4 v3 = sf[(size_t)s3 * CL];
        ACC8(v0); ACC8(v1); ACC8(v2); ACC8(v3);
    }
    for (; i < deg; ++i) {
        uint4 v = sf[(size_t)bk[i] * CL];
        ACC8(v);
    }
#undef ACC8
    float cj = rsqrtf((float)deg);
    uint4 o;
    o.x = bf16pack(acc[0] * cj, acc[1] * cj);
    o.y = bf16pack(acc[2] * cj, acc[3] * cj);
    o.z = bf16pack(acc[4] * cj, acc[5] * cj);
    o.w = bf16pack(acc[6] * cj, acc[7] * cj);
    *hout = o;
}

// Stage 6: out = h @ W + bias via mfma_f32_16x16x32_bf16. Zero LDS.
// Layouts (m89/m91-verified): A[m=lane&15][k=quad*8+j]; B[k=quad*8+j][n=lane&15];
// D col=lane&15, row=quad*4+reg.
__global__ void __launch_bounds__(256) mfma_mm_kernel(
        const uint4* __restrict__ hb4, const uint4* __restrict__ wt4,
        const float* __restrict__ bias, float* __restrict__ out) {
    int wave = threadIdx.x >> 6;
    int lane = threadIdx.x & 63;
    int tile = blockIdx.x * 4 + wave;
    if (tile >= NTILES) return;
    int m = lane & 15, quad = lane >> 4;
    int row0 = tile * 16;
    int rb = (row0 + m) * RL + quad;
    short8 a0 = as_short8(hb4[rb]);      // kc=0
    short8 a1 = as_short8(hb4[rb + 4]);  // kc=1
    short8 a2 = as_short8(hb4[rb + 8]);  // kc=2
    int r_out0 = row0 + quad * 4;
#pragma unroll
    for (int ct = 0; ct < 6; ++ct) {
        int n = ct * 16 + m;
        int wb = n * RL + quad;
        short8 b0 = as_short8(wt4[wb]);
        short8 b1 = as_short8(wt4[wb + 4]);
        short8 b2 = as_short8(wt4[wb + 8]);
        floatx4 c = {0.f, 0.f, 0.f, 0.f};
        c = __builtin_amdgcn_mfma_f32_16x16x32_bf16(a0, b0, c, 0, 0, 0);
        c = __builtin_amdgcn_mfma_f32_16x16x32_bf16(a1, b1, c, 0, 0, 0);
        c = __builtin_amdgcn_mfma_f32_16x16x32_bf16(a2, b2, c, 0, 0, 0);
        float bs = bias[n];
#pragma unroll
        for (int r = 0; r < 4; ++r)
            out[(size_t)(r_out0 + r) * D + n] = c[r] + bs;
    }
}

extern "C" void kernel_launch(void* const* d_in, const int* in_sizes, int n_in,
                              void* d_out, int out_size, void* d_ws, size_t ws_size,
                              hipStream_t stream) {
    const float* feat = (const float*)d_in[0];
    const float* W    = (const float*)d_in[1];
    const float* bias = (const float*)d_in[2];
    const int*   src  = (const int*)d_in[3];
    const int*   dst  = (const int*)d_in[4];

    // ws: hist 12.8MB | ci[N] | off[N] | deg_in[N] | blockSums[256] |
    //     csr[E] 3.2MB | sfeat 9.6MB (chunk-major) | hbuf 9.6MB | WT 18KB
    unsigned* hist      = (unsigned*)d_ws;
    float*    ci        = (float*)(hist + (size_t)2 * HB * NW);
    int*      off       = (int*)(ci + N_NODES);
    int*      deg_in    = off + N_NODES;
    int*      blockSums = deg_in + N_NODES;
    int*      csr       = blockSums + 256;
    uint4*    sfeat     = (uint4*)(csr + N_EDGES);
    uint4*    hbuf      = sfeat + (size_t)NPASS * N_NODES * CL;
    unsigned* WT32      = (unsigned*)(hbuf + (size_t)N_NODES * RL);

    hist_kernel<<<HB, 1024, 0, stream>>>(src, dst, hist);
    reduce_kernel<<<(NW + 255) / 256, 256, 0, stream>>>(hist, ci, deg_in);
    conv_kernel<<<(N_NODES * RL + 255) / 256, 256, 0, stream>>>(
        (const float4*)feat, ci, sfeat);
    wprep_kernel<<<(D * (D / 2) + 255) / 256, 256, 0, stream>>>(W, WT32);
    scanA_kernel<<<SCAN_BLK, 256, 0, stream>>>(deg_in, off, blockSums);
    scan_fin_kernel<<<SCAN_BLK, 256, 0, stream>>>(blockSums, off);
    fill_kernel<<<HB, 1024, 0, stream>>>(src, dst, off, hist, csr);
    dim3 ggrid((N_NODES + GN - 1) / GN, NPASS);
    gather_kernel<<<ggrid, 192, 0, stream>>>(
        (const float4*)feat, sfeat, deg_in, off, csr, hbuf);
    mfma_mm_kernel<<<(NTILES + 3) / 4, 256, 0, stream>>>(
        hbuf, (const uint4*)WT32, bias, (float*)d_out);
}

// Round 13
// 159.590 us; speedup vs baseline: 1.3225x; 1.0872x over previous
//
#include <hip/hip_runtime.h>

#define N_NODES 50000
#define N_EDGES 800000
#define D 96
#define D4 (D / 4)        // 24 float4 per row

#define HB 128                 // histogram blocks
#define CHUNK (N_EDGES / HB)   // 6250 edges per block
#define NW (N_NODES / 4)       // 12500 packed u32 words (4 x u8 counts)

#define RL 12                  // bf16 row = 96*2B = 12 uint4 per node row
#define NTILES (N_NODES / 16)  // 3125 16-row MFMA tiles
#define CONV_BLOCKS ((N_NODES * RL + 255) / 256)   // 2344
#define WPREP_BLOCKS ((D * (D / 2) + 255) / 256)   // 18

typedef __attribute__((ext_vector_type(8))) short short8;
typedef __attribute__((ext_vector_type(4))) float floatx4;

__device__ __forceinline__ short8 as_short8(uint4 u) { return *(short8*)&u; }

// Stage 1: degree counting, u8-packed full-range LDS hist, 2 phases (src,dst).
// Also zeroes the off-allocator counter (runs strictly before reduce).
__global__ void __launch_bounds__(1024) hist_kernel(
        const int* __restrict__ src, const int* __restrict__ dst,
        unsigned* __restrict__ hist, unsigned* __restrict__ total) {
    __shared__ unsigned hbin[NW];   // 48.8 KB
    int b = blockIdx.x, t = threadIdx.x;
    if (b == 0 && t == 0) *total = 0;
    int e0 = b * CHUNK;
#pragma unroll 1
    for (int p = 0; p < 2; ++p) {
        const int* __restrict__ arr = (p == 0) ? src : dst;
        for (int i = t; i < NW; i += 1024) hbin[i] = 0;
        __syncthreads();
        for (int i = t; i < CHUNK; i += 1024) {
            int l = arr[e0 + i];
            atomicAdd(&hbin[l >> 2], 1u << ((l & 3) * 8));
        }
        __syncthreads();
        unsigned* __restrict__ g = hist + ((size_t)p * HB + b) * NW;
        for (int i = t; i < NW; i += 1024) g[i] = hbin[i];
        __syncthreads();
    }
}

// Stage 2: src hists -> ci; dst hists -> deg_in + in-place exclusive prefix
// along the block dimension (packed u8, carry-free; totals <= ~45).
// ALSO assigns off[] directly: wave-level exclusive scan of 4-node degree
// sums + one atomicAdd per wave for the global base. CSR segment order is
// arbitrary but disjoint — that's all gather/fill need. Kills the scan kernels.
__global__ void __launch_bounds__(256) reduce_kernel(
        unsigned* __restrict__ hist, float* __restrict__ ci,
        int* __restrict__ deg_in, int* __restrict__ off,
        unsigned* __restrict__ total) {
    int w = blockIdx.x * 256 + threadIdx.x;
    bool valid = w < NW;
    unsigned acc_s = 0;
    int4 dv = {0, 0, 0, 0};
    if (valid) {
        const unsigned* __restrict__ ps = hist + w;
        unsigned* __restrict__ pd = hist + (size_t)HB * NW + w;
#pragma unroll 8
        for (int b = 0; b < HB; ++b) acc_s += ps[(size_t)b * NW];
        unsigned run = 0;
#pragma unroll 4
        for (int b = 0; b < HB; ++b) {
            unsigned v = pd[(size_t)b * NW];
            pd[(size_t)b * NW] = run;        // exclusive prefix, packed u8
            run += v;
        }
        dv.x = (int)( run        & 0xFFu);
        dv.y = (int)((run >>  8) & 0xFFu);
        dv.z = (int)((run >> 16) & 0xFFu);
        dv.w = (int)( run >> 24        );
    }
    int sum4 = dv.x + dv.y + dv.z + dv.w;
    int lane = threadIdx.x & 63;
    int incl = sum4;
#pragma unroll
    for (int st = 1; st < 64; st <<= 1) {
        int v = __shfl_up(incl, st, 64);
        if (lane >= st) incl += v;
    }
    int excl = incl - sum4;
    int wave_total = __shfl(incl, 63, 64);
    int base = 0;
    if (lane == 63) base = (int)atomicAdd(total, (unsigned)wave_total);
    base = __shfl(base, 63, 64);
    if (valid) {
        int n0 = 4 * w;
        int b0 = base + excl;
        int4 ov;
        ov.x = b0;
        ov.y = b0 + dv.x;
        ov.z = b0 + dv.x + dv.y;
        ov.w = b0 + dv.x + dv.y + dv.z;
        *(int4*)&off[n0] = ov;
        *(int4*)&deg_in[n0] = dv;
        float4 cv;
        cv.x = rsqrtf(fmaxf((float)( acc_s        & 0xFFu), 1.0f));
        cv.y = rsqrtf(fmaxf((float)((acc_s >>  8) & 0xFFu), 1.0f));
        cv.z = rsqrtf(fmaxf((float)((acc_s >> 16) & 0xFFu), 1.0f));
        cv.w = rsqrtf(fmaxf((float)( acc_s >> 24        ), 1.0f));
        *(float4*)&ci[n0] = cv;
    }
}

// bf16 RTNE pack: a -> low 16, b -> high 16.
__device__ __forceinline__ unsigned bf16pack(float a, float b) {
    unsigned ua = __float_as_uint(a);
    unsigned ub = __float_as_uint(b);
    ua = (ua + 0x7FFFu + ((ua >> 16) & 1u)) >> 16;       // RTNE
    ub = (ub + 0x7FFFu + ((ub >> 16) & 1u)) & 0xFFFF0000u;
    return ua | ub;
}

// Stage 3: sfeat[s] = bf16_rtne(ci[s] * feat[s]) (row-major), with the W
// transpose (WT[n][k] = bf16(W[k][n])) folded into the tail blocks.
__global__ void __launch_bounds__(256) conv_kernel(
        const float4* __restrict__ feat4, const float* __restrict__ ci,
        uint4* __restrict__ sfeat, const float* __restrict__ W,
        unsigned* __restrict__ WT32) {
    int blk = blockIdx.x;
    if (blk >= CONV_BLOCKS) {   // wprep tail
        int t = (blk - CONV_BLOCKS) * 256 + threadIdx.x;
        if (t >= D * (D / 2)) return;
        int n = t / (D / 2);
        int j = t - n * (D / 2);
        float w0 = W[(2 * j) * D + n];
        float w1 = W[(2 * j + 1) * D + n];
        WT32[n * (D / 2) + j] = bf16pack(w0, w1);
        return;
    }
    int t = blk * 256 + threadIdx.x;
    if (t >= N_NODES * RL) return;
    int n = t / RL;
    int lane = t - n * RL;
    float c = ci[n];
    float4 a = feat4[n * D4 + lane * 2];
    float4 b = feat4[n * D4 + lane * 2 + 1];
    uint4 o;
    o.x = bf16pack(a.x * c, a.y * c);
    o.y = bf16pack(a.z * c, a.w * c);
    o.z = bf16pack(b.x * c, b.y * c);
    o.w = bf16pack(b.z * c, b.w * c);
    sfeat[t] = o;
}

// Stage 4: atomic-free CSR fill via LDS cursors seeded from the prefix row.
__global__ void __launch_bounds__(1024) fill_kernel(
        const int* __restrict__ src, const int* __restrict__ dst,
        const int* __restrict__ off, const unsigned* __restrict__ hist,
        int* __restrict__ csr) {
    __shared__ unsigned cur[NW];   // 48.8 KB
    int b = blockIdx.x, t = threadIdx.x;
    const unsigned* __restrict__ pr = hist + ((size_t)HB + b) * NW;
    for (int i = t; i < NW; i += 1024) cur[i] = pr[i];
    __syncthreads();
    int e0 = b * CHUNK;
    for (int i = t; i < CHUNK; i += 1024) {
        int d = dst[e0 + i];
        int sh = (d & 3) * 8;
        unsigned old = atomicAdd(&cur[d >> 2], 1u << sh);
        int pos = (int)((old >> sh) & 0xFFu);
        csr[off[d] + pos] = src[e0 + i];
    }
}

// Stage 5: gather h = deg>0 ? cj * sum sfeat[s] : feat[n], write bf16 to hbuf.
// 12 lanes/node (one uint4 = 8 bf16 each), 16 nodes per 192-thread block.
__global__ void __launch_bounds__(192) gather_kernel(
        const float4* __restrict__ feat4, const uint4* __restrict__ sfeat,
        const int* __restrict__ deg_in, const int* __restrict__ off,
        const int* __restrict__ csr, uint4* __restrict__ hbuf) {
    int tid = threadIdx.x;
    int g = tid / RL;            // node 0..15
    int lane = tid - g * RL;     // uint4 index 0..11 (8 bf16)
    int n = blockIdx.x * 16 + g; // 3125*16 = 50000 exact
    int deg = deg_in[n];
    uint4* __restrict__ hout = hbuf + (size_t)n * RL + lane;
    if (deg == 0) {
        float4 a = feat4[n * D4 + lane * 2];
        float4 b = feat4[n * D4 + lane * 2 + 1];
        uint4 o;
        o.x = bf16pack(a.x, a.y);
        o.y = bf16pack(a.z, a.w);
        o.z = bf16pack(b.x, b.y);
        o.w = bf16pack(b.z, b.w);
        *hout = o;
        return;
    }
    const int* bk = csr + off[n];
    const uint4* __restrict__ sf = sfeat + lane;
    float acc[8] = {};
#define ACC8(v)  { \
    acc[0] += __uint_as_float((v).x << 16); \
    acc[1] += __uint_as_float((v).x & 0xFFFF0000u); \
    acc[2] += __uint_as_float((v).y << 16); \
    acc[3] += __uint_as_float((v).y & 0xFFFF0000u); \
    acc[4] += __uint_as_float((v).z << 16); \
    acc[5] += __uint_as_float((v).z & 0xFFFF0000u); \
    acc[6] += __uint_as_float((v).w << 16); \
    acc[7] += __uint_as_float((v).w & 0xFFFF0000u); }
    int i = 0;
    for (; i + 3 < deg; i += 4) {
        int s0 = bk[i], s1 = bk[i + 1], s2 = bk[i + 2], s3 = bk[i + 3];
        uint4 v0 = sf[(size_t)s0 * RL];
        uint4 v1 = sf[(size_t)s1 * RL];
        uint4 v2 = sf[(size_t)s2 * RL];
        uint4 v3 = sf[(size_t)s3 * RL];
        ACC8(v0); ACC8(v1); ACC8(v2); ACC8(v3);
    }
    for (; i < deg; ++i) {
        uint4 v = sf[(size_t)bk[i] * RL];
        ACC8(v);
    }
#undef ACC8
    float cj = rsqrtf((float)deg);
    uint4 o;
    o.x = bf16pack(acc[0] * cj, acc[1] * cj);
    o.y = bf16pack(acc[2] * cj, acc[3] * cj);
    o.z = bf16pack(acc[4] * cj, acc[5] * cj);
    o.w = bf16pack(acc[6] * cj, acc[7] * cj);
    *hout = o;
}

// Stage 6: out = h @ W + bias via mfma_f32_16x16x32_bf16. Zero LDS.
// Layouts (m89/m91-verified): A[m=lane&15][k=quad*8+j]; B[k=quad*8+j][n=lane&15];
// D col=lane&15, row=quad*4+reg.
__global__ void __launch_bounds__(256) mfma_mm_kernel(
        const uint4* __restrict__ hb4, const uint4* __restrict__ wt4,
        const float* __restrict__ bias, float* __restrict__ out) {
    int wave = threadIdx.x >> 6;
    int lane = threadIdx.x & 63;
    int tile = blockIdx.x * 4 + wave;
    if (tile >= NTILES) return;
    int m = lane & 15, quad = lane >> 4;
    int row0 = tile * 16;
    int rb = (row0 + m) * RL + quad;
    short8 a0 = as_short8(hb4[rb]);      // kc=0
    short8 a1 = as_short8(hb4[rb + 4]);  // kc=1
    short8 a2 = as_short8(hb4[rb + 8]);  // kc=2
    int r_out0 = row0 + quad * 4;
#pragma unroll
    for (int ct = 0; ct < 6; ++ct) {
        int n = ct * 16 + m;
        int wb = n * RL + quad;
        short8 b0 = as_short8(wt4[wb]);
        short8 b1 = as_short8(wt4[wb + 4]);
        short8 b2 = as_short8(wt4[wb + 8]);
        floatx4 c = {0.f, 0.f, 0.f, 0.f};
        c = __builtin_amdgcn_mfma_f32_16x16x32_bf16(a0, b0, c, 0, 0, 0);
        c = __builtin_amdgcn_mfma_f32_16x16x32_bf16(a1, b1, c, 0, 0, 0);
        c = __builtin_amdgcn_mfma_f32_16x16x32_bf16(a2, b2, c, 0, 0, 0);
        float bs = bias[n];
#pragma unroll
        for (int r = 0; r < 4; ++r)
            out[(size_t)(r_out0 + r) * D + n] = c[r] + bs;
    }
}

extern "C" void kernel_launch(void* const* d_in, const int* in_sizes, int n_in,
                              void* d_out, int out_size, void* d_ws, size_t ws_size,
                              hipStream_t stream) {
    const float* feat = (const float*)d_in[0];
    const float* W    = (const float*)d_in[1];
    const float* bias = (const float*)d_in[2];
    const int*   src  = (const int*)d_in[3];
    const int*   dst  = (const int*)d_in[4];

    // ws: hist 12.8MB | ci[N] | off[N] | deg_in[N] | csr[E] 3.2MB |
    //     sfeat 9.6MB | hbuf 9.6MB | WT 18KB | total[1]
    unsigned* hist   = (unsigned*)d_ws;
    float*    ci     = (float*)(hist + (size_t)2 * HB * NW);
    int*      off    = (int*)(ci + N_NODES);
    int*      deg_in = off + N_NODES;
    int*      csr    = deg_in + N_NODES;
    uint4*    sfeat  = (uint4*)(csr + N_EDGES);
    uint4*    hbuf   = sfeat + (size_t)N_NODES * RL;
    unsigned* WT32   = (unsigned*)(hbuf + (size_t)N_NODES * RL);
    unsigned* total  = WT32 + D * (D / 2);

    hist_kernel<<<HB, 1024, 0, stream>>>(src, dst, hist, total);
    reduce_kernel<<<(NW + 255) / 256, 256, 0, stream>>>(hist, ci, deg_in, off, total);
    conv_kernel<<<CONV_BLOCKS + WPREP_BLOCKS, 256, 0, stream>>>(
        (const float4*)feat, ci, sfeat, W, WT32);
    fill_kernel<<<HB, 1024, 0, stream>>>(src, dst, off, hist, csr);
    gather_kernel<<<N_NODES / 16, 192, 0, stream>>>(
        (const float4*)feat, sfeat, deg_in, off, csr, hbuf);
    mfma_mm_kernel<<<(NTILES + 3) / 4, 256, 0, stream>>>(
        hbuf, (const uint4*)WT32, bias, (float*)d_out);
}